// Round 1
// baseline (8203.418 us; speedup 1.0000x reference)
//
#include <hip/hip_runtime.h>
#include <math.h>

// LSTMPredictor: B=2048 rows, 3x LSTMCell(H=50), P=17, T=512 + 32 future steps.
// fp32 buffers (runtime-sniffed, bf16 fallback kept). One block per CU owns M=8
// batch rows for the whole 544-step recurrence.
//
// R1 restructure vs previous best (3823 us):
//   thread = (single gate g, K-fifth q) : 1000/1024 active (was 400/512)
//   -> per-thread weights 54 floats (was 134): fits in VGPRs, kills the
//      v_accvgpr_read shuffle that doubled VALU issue at VGPR_Count=128
//   -> 16 waves/CU (4/SIMD, occupancy ~48%) to hide barrier/LDS latency
//   gb relaid [q][gate][m]: gate stores = 2x ds_write_b128, update reads are
//   bank-sequential (addr%32==lane) -> conflict-free.

#define BATCH    2048
#define PP       17
#define HH       50
#define GG       200      // 4*H
#define MROWS    8
#define NQ       5        // K split into fifths
#define NTHREADS 1024
#define NBLOCKS  (BATCH / MROWS)   // 256
#define TQ1      14       // cell1 K=68 (x17 + h50 + pad) -> 5*14=70
#define TQ2      20       // cell2 K=100 exact
#define TQ3      20       // cell3 K=100 exact

__device__ __forceinline__ float bf2f(unsigned short u) {
    unsigned int i = ((unsigned int)u) << 16;
    float f; __builtin_memcpy(&f, &i, 4); return f;
}
__device__ __forceinline__ unsigned short f2bf(float f) {
    unsigned int i; __builtin_memcpy(&i, &f, 4);
    return (unsigned short)((i + 0x7fffu + ((i >> 16) & 1u)) >> 16);
}
__device__ __forceinline__ float ldin(const void* p, long i, bool f32) {
    return f32 ? ((const float*)p)[i] : bf2f(((const unsigned short*)p)[i]);
}
// saturation-safe fast sigmoid/tanh (v_exp_f32 + v_rcp_f32)
__device__ __forceinline__ float fsig(float x) {
    float t = exp2f(-1.44269504089f * x);          // +inf at x->-inf, 0 at x->+inf
    return __builtin_amdgcn_rcpf(1.0f + t);        // 0 / 1 at the limits
}
__device__ __forceinline__ float ftanh(float x) {
    float t = exp2f(2.88539008178f * x);           // e^(2x)
    return 1.0f - 2.0f * __builtin_amdgcn_rcpf(t + 1.0f);   // -1 / +1 at the limits
}

// ---- dtype sniffer: bf16 weights decode to |v|<=0.142; fp32-as-bf16 gives junk ----
extern "C" __global__ void sniff_dtype(const unsigned short* __restrict__ w,
                                       int* __restrict__ flag) {
    int lane = threadIdx.x;
    bool bad = false;
#pragma unroll
    for (int t = 0; t < 4; ++t) {
        float v = bf2f(w[lane * 4 + t]);
        bad |= !(fabsf(v) <= 1.0f);
    }
    unsigned long long m = __ballot(bad);
    if (lane == 0) flag[0] = (m != 0ULL) ? 1 : 0;   // 1 => fp32 buffers
}

// gate phase: thread (g, q) accumulates the K-fifth partial of gate g for all
// 8 rows. Weights in registers; state reads are wave-uniform LDS broadcasts
// (2-address gather in the 4 fifth-boundary waves).
template <int TQ>
__device__ __forceinline__ void gate_phase(const float* __restrict__ S,
                                           float* __restrict__ gb,
                                           const float w[TQ],
                                           int srow, int g, int q, bool active) {
    if (active) {
        float a[8] = {0, 0, 0, 0, 0, 0, 0, 0};
        const float4* Sp = (const float4*)(S + (srow + q * TQ) * MROWS);
#pragma unroll
        for (int t = 0; t < TQ; ++t) {
            float wv = w[t];
            float4 lo = Sp[2 * t];         // broadcast read (rows m=0..3)
            float4 hi = Sp[2 * t + 1];     // rows m=4..7
            a[0] = fmaf(wv, lo.x, a[0]); a[1] = fmaf(wv, lo.y, a[1]);
            a[2] = fmaf(wv, lo.z, a[2]); a[3] = fmaf(wv, lo.w, a[3]);
            a[4] = fmaf(wv, hi.x, a[4]); a[5] = fmaf(wv, hi.y, a[5]);
            a[6] = fmaf(wv, hi.z, a[6]); a[7] = fmaf(wv, hi.w, a[7]);
        }
        // gb[q][g][m]: m contiguous -> two b128 stores
        float4* d = (float4*)(gb + (q * GG + g) * MROWS);
        d[0] = make_float4(a[0], a[1], a[2], a[3]);
        d[1] = make_float4(a[4], a[5], a[6], a[7]);
    }
}

__device__ __forceinline__ void lstm_update(float* __restrict__ S,
                                            const float* __restrict__ gb,
                                            const float* __restrict__ bs,
                                            float& c, int hrow, int tid) {
    // caller guards tid < 400;  m = tid&7 (conflict-free h write), j = tid>>3
    int m = tid & 7;
    int j = tid >> 3;
    float ii = bs[j], ff = bs[50 + j], gg = bs[100 + j], oo = bs[150 + j];
#pragma unroll
    for (int q = 0; q < NQ; ++q) {
        // addr%32 == lane within each read -> conflict-free
        const float* b = gb + q * (GG * MROWS) + m;
        ii += b[j * 8]; ff += b[(50 + j) * 8];
        gg += b[(100 + j) * 8]; oo += b[(150 + j) * 8];
    }
    float cn = fsig(ff) * c + fsig(ii) * ftanh(gg);
    c = cn;
    S[(hrow + j) * MROWS + m] = fsig(oo) * ftanh(cn);   // addr = hrow*8 + tid
}

extern "C" __global__ void __launch_bounds__(NTHREADS, 4)
lstm_persistent(const void* __restrict__ x,
                const void* __restrict__ wih1, const void* __restrict__ whh1,
                const void* __restrict__ bih1, const void* __restrict__ bhh1,
                const void* __restrict__ wih2, const void* __restrict__ whh2,
                const void* __restrict__ bih2, const void* __restrict__ bhh2,
                const void* __restrict__ wih3, const void* __restrict__ whh3,
                const void* __restrict__ bih3, const void* __restrict__ bhh3,
                const void* __restrict__ wlin, const void* __restrict__ blin,
                void* __restrict__ out, const int* __restrict__ flag,
                int T, int steps)
{
    const int tid = threadIdx.x;
    __shared__ float S[167 * MROWS];        // 0..16 x | 17..66 h1 | 67..116 h2 | 117..166 h3
    __shared__ float gb[NQ * GG * MROWS];   // [fifth][gate][m]  (32 KB)
    __shared__ float WLt[50 * PP];          // W_lin^T
    __shared__ float bs1[GG], bs2[GG], bs3[GG], bl[PP];

    const bool f32 = (flag[0] != 0);

    const int q = tid / GG;                 // K-fifth (wave-uniform except 4 boundary waves)
    const int g = tid - q * GG;             // gate index 0..199
    const bool active = (tid < NQ * GG);    // 1000 of 1024

    // ---- per-thread register weights (fp32, full precision): 54 floats ----
    float w1[TQ1], w2[TQ2], w3[TQ3];
    if (active) {
#pragma unroll
        for (int t = 0; t < TQ1; ++t) {              // cell1 K=68 (rows 68,69 zero-pad)
            int k = q * TQ1 + t;
            w1[t] = (k < 17) ? ldin(wih1, (long)g * 17 + k, f32)
                  : (k < 67) ? ldin(whh1, (long)g * 50 + (k - 17), f32)
                             : 0.0f;
        }
#pragma unroll
        for (int t = 0; t < TQ2; ++t) {              // cell2 K=100
            int k = q * TQ2 + t;
            w2[t] = (k < 50) ? ldin(wih2, (long)g * 50 + k, f32)
                             : ldin(whh2, (long)g * 50 + (k - 50), f32);
        }
#pragma unroll
        for (int t = 0; t < TQ3; ++t) {              // cell3 K=100
            int k = q * TQ3 + t;
            w3[t] = (k < 50) ? ldin(wih3, (long)g * 50 + k, f32)
                             : ldin(whh3, (long)g * 50 + (k - 50), f32);
        }
    }

    // ---- stage biases, W_lin^T, zero h-state, preload x(step 0) ----
    if (tid < GG) {
        bs1[tid] = ldin(bih1, tid, f32) + ldin(bhh1, tid, f32);
        bs2[tid] = ldin(bih2, tid, f32) + ldin(bhh2, tid, f32);
        bs3[tid] = ldin(bih3, tid, f32) + ldin(bhh3, tid, f32);
    } else if (tid < GG + PP) {
        bl[tid - GG] = ldin(blin, tid - GG, f32);
    }
    for (int i = tid; i < 50 * PP; i += NTHREADS) {
        int k = i / PP, p = i - k * PP;
        WLt[i] = ldin(wlin, (long)p * 50 + k, f32);
    }
    for (int i = tid; i < 1200; i += NTHREADS) S[136 + i] = 0.0f;   // h1,h2,h3 = 0

    const long rowBase = (long)blockIdx.x * MROWS;
    const long xStride = (long)T * PP;
    if (tid < 136) {
        int m = tid / PP, p = tid - (tid / PP) * PP;
        S[p * MROWS + m] = ldin(x, (rowBase + m) * xStride + p, f32);
    }
    float c1 = 0.0f, c2 = 0.0f, c3 = 0.0f;
    __syncthreads();

    const long outStride = (long)steps * PP;
    for (int s = 0; s < steps; ++s) {
        gate_phase<TQ1>(S, gb, w1, 0, g, q, active);            // cell1: [x|h1]
        __syncthreads();
        if (tid < 400) lstm_update(S, gb, bs1, c1, 17, tid);    // write h1
        __syncthreads();
        gate_phase<TQ2>(S, gb, w2, 17, g, q, active);           // cell2: [h1|h2]
        __syncthreads();
        if (tid < 400) lstm_update(S, gb, bs2, c2, 67, tid);    // write h2
        __syncthreads();
        gate_phase<TQ3>(S, gb, w3, 67, g, q, active);           // cell3: [h2|h3]
        __syncthreads();
        if (tid < 400) lstm_update(S, gb, bs3, c3, 117, tid);   // write h3
        __syncthreads();
        // ---- linear head + output + next input (feedback or global x) ----
        if (tid < 136) {
            int m = tid / PP, p = tid - (tid / PP) * PP;
            float acc = bl[p];
#pragma unroll
            for (int k = 0; k < 50; ++k)
                acc = fmaf(WLt[k * PP + p], S[(117 + k) * MROWS + m], acc);
            long oi = (rowBase + m) * outStride + (long)s * PP + p;
            if (f32) ((float*)out)[oi] = acc;
            else     ((unsigned short*)out)[oi] = f2bf(acc);
            if (s + 1 >= T && s + 1 < steps)                    // autoregressive feedback
                S[p * MROWS + m] = acc;
        } else if (tid >= 256 && tid < 392) {
            int u = tid - 256;
            int m = u / PP, p = u - (u / PP) * PP;
            if (s + 1 < T)                                      // prefetch next x chunk
                S[p * MROWS + m] = ldin(x, (rowBase + m) * xStride + (long)(s + 1) * PP + p, f32);
        }
        __syncthreads();
    }
}

extern "C" void kernel_launch(void* const* d_in, const int* in_sizes, int n_in,
                              void* d_out, int out_size, void* d_ws, size_t ws_size,
                              hipStream_t stream) {
    (void)ws_size; (void)n_in;
    int* flag = (int*)d_ws;

    const int T     = in_sizes[0] / (BATCH * PP);   // 512
    const int steps = out_size / (BATCH * PP);      // 544

    sniff_dtype<<<1, 64, 0, stream>>>((const unsigned short*)d_in[1], flag);

    lstm_persistent<<<NBLOCKS, NTHREADS, 0, stream>>>(
        d_in[0],
        d_in[1], d_in[2], d_in[3], d_in[4],
        d_in[5], d_in[6], d_in[7], d_in[8],
        d_in[9], d_in[10], d_in[11], d_in[12],
        d_in[13], d_in[14],
        d_out, flag, T, steps);
}